// Round 1
// baseline (2006.097 us; speedup 1.0000x reference)
//
#include <hip/hip_runtime.h>
#include <hip/hip_bf16.h>

#define HD 128
#define NEG_SLOPE 0.2f

// ---------- ordered-float helpers for atomic max on fp32 ----------
__device__ __forceinline__ unsigned f2ord(float f) {
    unsigned u = __float_as_uint(f);
    return (u & 0x80000000u) ? ~u : (u | 0x80000000u);
}
__device__ __forceinline__ float ord2f(unsigned u) {
    unsigned v = (u & 0x80000000u) ? (u & 0x7fffffffu) : ~u;
    return __uint_as_float(v);
}

__device__ __forceinline__ float lrelu(float x) {
    return x > 0.f ? x : NEG_SLOPE * x;
}

// ---------- init d_out with biases ----------
// rows [0,Na): b[1];  rows [Na,Na+Nw): b[0]+b[2]
__global__ void k_init_out(float* __restrict__ out, const float* __restrict__ b,
                           int Na, int Nw) {
    long long idx = (long long)blockIdx.x * blockDim.x + threadIdx.x; // float4 units
    long long total4 = (long long)(Na + Nw) * (HD / 4);
    if (idx >= total4) return;
    int col4 = (int)(idx & (HD / 4 - 1));
    long long row = idx >> 5; // /32
    float4 bv;
    if (row < Na) {
        bv = *(const float4*)&b[1 * HD + col4 * 4];
    } else {
        float4 v0 = *(const float4*)&b[0 * HD + col4 * 4];
        float4 v2 = *(const float4*)&b[2 * HD + col4 * 4];
        bv = make_float4(v0.x + v2.x, v0.y + v2.y, v0.z + v2.z, v0.w + v2.w);
    }
    *(float4*)&out[idx * 4] = bv;
}

__global__ void k_relu(float* __restrict__ out, long long total4) {
    long long idx = (long long)blockIdx.x * blockDim.x + threadIdx.x;
    if (idx >= total4) return;
    float4 v = *(float4*)&out[idx * 4];
    v.x = fmaxf(v.x, 0.f); v.y = fmaxf(v.y, 0.f);
    v.z = fmaxf(v.z, 0.f); v.w = fmaxf(v.w, 0.f);
    *(float4*)&out[idx * 4] = v;
}

__global__ void k_zero_stats(unsigned* __restrict__ emaxU, float* __restrict__ den, int n) {
    int idx = blockIdx.x * blockDim.x + threadIdx.x;
    if (idx >= n) return;
    emaxU[idx] = 0u;          // ordered-space minimum
    den[idx] = 0.f;
}

// ---------- v[c][sd][d] = sum_h W[c][d][h] * a[c][h] ----------
__global__ void k_vvec(const float* __restrict__ Ws, const float* __restrict__ Wd,
                       const float* __restrict__ a_s, const float* __restrict__ a_d,
                       float* __restrict__ v) {
    int t = blockIdx.x * blockDim.x + threadIdx.x;
    if (t >= 3 * 2 * HD) return;
    int c = t >> 8;
    int sd = (t >> 7) & 1;
    int d = t & (HD - 1);
    const float* W = sd ? Wd : Ws;
    const float* a = sd ? a_d : a_s;
    const float* Wrow = W + ((size_t)c * HD + d) * HD;
    const float* av = a + c * HD;
    float s = 0.f;
    for (int h = 0; h < HD; h++) s += Wrow[h] * av[h];
    v[t] = s;
}

// ---------- alpha[n] = x[n] . v[slot]  (up to 4 slots fused in one pass) ----------
__global__ void k_alpha(const float* __restrict__ x, int N,
                        const float* __restrict__ v,
                        int i0, int i1, int i2, int i3,
                        float* __restrict__ o0, float* __restrict__ o1,
                        float* __restrict__ o2, float* __restrict__ o3, int nv) {
    int lane = threadIdx.x & 63;
    int wid = (int)(((long long)blockIdx.x * blockDim.x + threadIdx.x) >> 6);
    int nwaves = (gridDim.x * blockDim.x) >> 6;
    float2 z = make_float2(0.f, 0.f);
    float2 vv0 = *(const float2*)&v[i0 * HD + lane * 2];
    float2 vv1 = (nv > 1) ? *(const float2*)&v[i1 * HD + lane * 2] : z;
    float2 vv2 = (nv > 2) ? *(const float2*)&v[i2 * HD + lane * 2] : z;
    float2 vv3 = (nv > 3) ? *(const float2*)&v[i3 * HD + lane * 2] : z;
    for (int n = wid; n < N; n += nwaves) {
        float2 xv = *(const float2*)&x[(long long)n * HD + lane * 2];
        float s0 = xv.x * vv0.x + xv.y * vv0.y;
        float s1 = xv.x * vv1.x + xv.y * vv1.y;
        float s2 = xv.x * vv2.x + xv.y * vv2.y;
        float s3 = xv.x * vv3.x + xv.y * vv3.y;
        #pragma unroll
        for (int off = 32; off; off >>= 1) {
            s0 += __shfl_xor(s0, off, 64);
            s1 += __shfl_xor(s1, off, 64);
            s2 += __shfl_xor(s2, off, 64);
            s3 += __shfl_xor(s3, off, 64);
        }
        if (lane == 0) {
            o0[n] = s0;
            if (nv > 1) o1[n] = s1;
            if (nv > 2) o2[n] = s2;
            if (nv > 3) o3[n] = s3;
        }
    }
}

// ---------- H[nrows x 128] = X[nrows x 128] * W[128 x 128], fp32 ----------
__global__ __launch_bounds__(256) void k_gemm128(const float* __restrict__ X,
                                                 const float* __restrict__ W,
                                                 float* __restrict__ Hout, int nrows) {
    __shared__ float Wsh[32][132];
    __shared__ float Xsh[64][36];
    const int tid = threadIdx.x;
    const int tx = tid & 15;   // 16 col-groups x 8 cols
    const int ty = tid >> 4;   // 16 row-groups x 4 rows
    const long long row0 = (long long)blockIdx.x * 64;
    float acc[4][8];
    #pragma unroll
    for (int r = 0; r < 4; r++)
        #pragma unroll
        for (int c = 0; c < 8; c++) acc[r][c] = 0.f;

    for (int kk = 0; kk < HD; kk += 32) {
        #pragma unroll
        for (int i = 0; i < 4; i++) {           // W panel: 32x128 = 1024 float4
            int t = tid + i * 256;
            int r = t >> 5;
            int c4 = t & 31;
            float4 w4 = *(const float4*)&W[(size_t)(kk + r) * HD + c4 * 4];
            *(float4*)&Wsh[r][c4 * 4] = w4;
        }
        #pragma unroll
        for (int i = 0; i < 2; i++) {           // X panel: 64x32 = 512 float4
            int t = tid + i * 256;
            int r = t >> 3;
            int c4 = t & 7;
            long long gr = row0 + r;
            float4 x4 = make_float4(0.f, 0.f, 0.f, 0.f);
            if (gr < nrows) x4 = *(const float4*)&X[gr * HD + kk + c4 * 4];
            *(float4*)&Xsh[r][c4 * 4] = x4;
        }
        __syncthreads();
        #pragma unroll
        for (int k = 0; k < 32; k++) {
            float xv[4];
            #pragma unroll
            for (int r = 0; r < 4; r++) xv[r] = Xsh[ty * 4 + r][k];
            float4 wa = *(float4*)&Wsh[k][tx * 8];
            float4 wb = *(float4*)&Wsh[k][tx * 8 + 4];
            float wreg[8] = {wa.x, wa.y, wa.z, wa.w, wb.x, wb.y, wb.z, wb.w};
            #pragma unroll
            for (int r = 0; r < 4; r++)
                #pragma unroll
                for (int c = 0; c < 8; c++) acc[r][c] += xv[r] * wreg[c];
        }
        __syncthreads();
    }
    #pragma unroll
    for (int r = 0; r < 4; r++) {
        long long gr = row0 + ty * 4 + r;
        if (gr < nrows) {
            *(float4*)&Hout[gr * HD + tx * 8] =
                make_float4(acc[r][0], acc[r][1], acc[r][2], acc[r][3]);
            *(float4*)&Hout[gr * HD + tx * 8 + 4] =
                make_float4(acc[r][4], acc[r][5], acc[r][6], acc[r][7]);
        }
    }
}

// ---------- edge pass 1: segment max of leaky_relu(as[src]+ad[dst]) ----------
__global__ void k_edge_max(const int* __restrict__ src, const int* __restrict__ dst,
                           const float* __restrict__ as_, const float* __restrict__ ad_,
                           unsigned* __restrict__ emaxU, int E) {
    int e = blockIdx.x * blockDim.x + threadIdx.x;
    if (e >= E) return;
    float ev = lrelu(as_[src[e]] + ad_[dst[e]]);
    atomicMax(&emaxU[dst[e]], f2ord(ev));
}

// ---------- edge pass 2: den[dst] += exp(e - emax[dst]) ----------
__global__ void k_edge_den(const int* __restrict__ src, const int* __restrict__ dst,
                           const float* __restrict__ as_, const float* __restrict__ ad_,
                           const unsigned* __restrict__ emaxU, float* __restrict__ den, int E) {
    int e = blockIdx.x * blockDim.x + threadIdx.x;
    if (e >= E) return;
    int d = dst[e];
    float ev = lrelu(as_[src[e]] + ad_[d]);
    atomicAdd(&den[d], __expf(ev - ord2f(emaxU[d])));
}

// ---------- edge pass 3: out[dst] += (w/den) * hs[src], wave per edge ----------
__global__ void k_edge_scatter(const int* __restrict__ src, const int* __restrict__ dst,
                               const float* __restrict__ as_, const float* __restrict__ ad_,
                               const unsigned* __restrict__ emaxU, const float* __restrict__ den,
                               const float* __restrict__ hs, float* __restrict__ out, int E) {
    int lane = threadIdx.x & 63;
    int wid = (int)(((long long)blockIdx.x * blockDim.x + threadIdx.x) >> 6);
    int nwaves = (gridDim.x * blockDim.x) >> 6;
    for (int e = wid; e < E; e += nwaves) {
        int s = src[e];
        int d = dst[e];
        float ev = lrelu(as_[s] + ad_[d]);
        float coef = __expf(ev - ord2f(emaxU[d])) / den[d]; // den >= 1 always
        float2 h = *(const float2*)&hs[(long long)s * HD + lane * 2];
        atomicAdd(&out[(long long)d * HD + lane * 2], coef * h.x);
        atomicAdd(&out[(long long)d * HD + lane * 2 + 1], coef * h.y);
    }
}

extern "C" void kernel_launch(void* const* d_in, const int* in_sizes, int n_in,
                              void* d_out, int out_size, void* d_ws, size_t ws_size,
                              hipStream_t stream) {
    const float* x_artist  = (const float*)d_in[0];
    const float* x_artwork = (const float*)d_in[1];
    const int* srcA[3] = {(const int*)d_in[2], (const int*)d_in[4], (const int*)d_in[6]};
    const int* dstA[3] = {(const int*)d_in[3], (const int*)d_in[5], (const int*)d_in[7]};
    const float* Ws  = (const float*)d_in[8];
    const float* Wd  = (const float*)d_in[9];
    const float* a_s = (const float*)d_in[10];
    const float* a_d = (const float*)d_in[11];
    const float* b   = (const float*)d_in[12];
    float* out = (float*)d_out;

    const int Na = in_sizes[0] / HD;
    const int Nw = in_sizes[1] / HD;
    const int E  = in_sizes[2];
    const int nStats = 2 * Nw + Na;

    // ---- workspace carve-up (floats) ----
    float* ws = (float*)d_ws;
    size_t off = 0;
    float* v = ws + off;            off += 768;
    float* as0 = ws + off;          off += Na;
    float* ad0 = ws + off;          off += Nw;
    float* as1 = ws + off;          off += Nw;
    float* ad1 = ws + off;          off += Na;
    float* as2 = ws + off;          off += Nw;
    float* ad2 = ws + off;          off += Nw;
    unsigned* emaxU = (unsigned*)(ws + off); off += nStats;
    float* den = ws + off;          off += nStats;
    float* hs = ws + off;           off += (size_t)Nw * HD;
    if (ws_size < off * sizeof(float)) return; // scratch too small — cannot run

    // per-conv metadata
    const float* xsrc[3]  = {x_artist, x_artwork, x_artwork};
    const int    nsrc[3]  = {Na, Nw, Nw};
    const float* asP[3]   = {as0, as1, as2};
    const float* adP[3]   = {ad0, ad1, ad2};
    const int statOff[3]  = {0, Nw, Nw + Na};
    const int ndst[3]     = {Nw, Na, Nw};
    const long long outBase[3] = {(long long)Na * HD, 0, (long long)Na * HD};

    const long long total4 = (long long)(Na + Nw) * (HD / 4);
    const int B = 256;

    k_init_out<<<(unsigned)((total4 + B - 1) / B), B, 0, stream>>>(out, b, Na, Nw);
    k_zero_stats<<<(nStats + B - 1) / B, B, 0, stream>>>(emaxU, den, nStats);
    k_vvec<<<3, B, 0, stream>>>(Ws, Wd, a_s, a_d, v);

    // alphas: artist pass (slots vs0=0, vd1=3), artwork pass (vd0=1, vs1=2, vs2=4, vd2=5)
    k_alpha<<<1024, B, 0, stream>>>(x_artist, Na, v, 0, 3, 0, 0, as0, ad1, nullptr, nullptr, 2);
    k_alpha<<<1024, B, 0, stream>>>(x_artwork, Nw, v, 1, 2, 4, 5, ad0, as1, as2, ad2, 4);

    // edge passes 1 & 2 for all convs (depend only on alphas)
    for (int c = 0; c < 3; c++)
        k_edge_max<<<(E + B - 1) / B, B, 0, stream>>>(srcA[c], dstA[c], asP[c], adP[c],
                                                      emaxU + statOff[c], E);
    for (int c = 0; c < 3; c++)
        k_edge_den<<<(E + B - 1) / B, B, 0, stream>>>(srcA[c], dstA[c], asP[c], adP[c],
                                                      emaxU + statOff[c], den + statOff[c], E);

    // per conv: hs GEMM (shared scratch) then normalized scatter into d_out
    for (int c = 0; c < 3; c++) {
        k_gemm128<<<(nsrc[c] + 63) / 64, B, 0, stream>>>(xsrc[c], Ws + (size_t)c * HD * HD,
                                                         hs, nsrc[c]);
        k_edge_scatter<<<4096, B, 0, stream>>>(srcA[c], dstA[c], asP[c], adP[c],
                                               emaxU + statOff[c], den + statOff[c],
                                               hs, out + outBase[c], E);
    }

    k_relu<<<(unsigned)((total4 + B - 1) / B), B, 0, stream>>>(out, total4);
}

// Round 2
// 663.332 us; speedup vs baseline: 3.0243x; 3.0243x over previous
//
#include <hip/hip_runtime.h>
#include <hip/hip_bf16.h>

#define HD 128
#define NEG_SLOPE 0.2f

__device__ __forceinline__ float lrelu(float x) {
    return x > 0.f ? x : NEG_SLOPE * x;
}

// ---------- init d_out with biases ----------
// rows [0,Na): b[1];  rows [Na,Na+Nw): b[0]+b[2]
__global__ void k_init_out(float* __restrict__ out, const float* __restrict__ b,
                           int Na, int Nw) {
    long long idx = (long long)blockIdx.x * blockDim.x + threadIdx.x; // float4 units
    long long total4 = (long long)(Na + Nw) * (HD / 4);
    if (idx >= total4) return;
    int col4 = (int)(idx & (HD / 4 - 1));
    long long row = idx >> 5; // /32
    float4 bv;
    if (row < Na) {
        bv = *(const float4*)&b[1 * HD + col4 * 4];
    } else {
        float4 v0 = *(const float4*)&b[0 * HD + col4 * 4];
        float4 v2 = *(const float4*)&b[2 * HD + col4 * 4];
        bv = make_float4(v0.x + v2.x, v0.y + v2.y, v0.z + v2.z, v0.w + v2.w);
    }
    *(float4*)&out[idx * 4] = bv;
}

__global__ void k_relu(float* __restrict__ out, long long total4) {
    long long idx = (long long)blockIdx.x * blockDim.x + threadIdx.x;
    if (idx >= total4) return;
    float4 v = *(float4*)&out[idx * 4];
    v.x = fmaxf(v.x, 0.f); v.y = fmaxf(v.y, 0.f);
    v.z = fmaxf(v.z, 0.f); v.w = fmaxf(v.w, 0.f);
    *(float4*)&out[idx * 4] = v;
}

__global__ void k_zero_int(int* __restrict__ p, int n) {
    int idx = blockIdx.x * blockDim.x + threadIdx.x;
    if (idx < n) p[idx] = 0;
}

// ---------- v[c][sd][d] = sum_h W[c][d][h] * a[c][h] ----------
__global__ void k_vvec(const float* __restrict__ Ws, const float* __restrict__ Wd,
                       const float* __restrict__ a_s, const float* __restrict__ a_d,
                       float* __restrict__ v) {
    int t = blockIdx.x * blockDim.x + threadIdx.x;
    if (t >= 3 * 2 * HD) return;
    int c = t >> 8;
    int sd = (t >> 7) & 1;
    int d = t & (HD - 1);
    const float* W = sd ? Wd : Ws;
    const float* a = sd ? a_d : a_s;
    const float* Wrow = W + ((size_t)c * HD + d) * HD;
    const float* av = a + c * HD;
    float s = 0.f;
    for (int h = 0; h < HD; h++) s += Wrow[h] * av[h];
    v[t] = s;
}

// ---------- alpha[n] = x[n] . v[slot]  (up to 4 slots fused in one pass) ----------
__global__ void k_alpha(const float* __restrict__ x, int N,
                        const float* __restrict__ v,
                        int i0, int i1, int i2, int i3,
                        float* __restrict__ o0, float* __restrict__ o1,
                        float* __restrict__ o2, float* __restrict__ o3, int nv) {
    int lane = threadIdx.x & 63;
    int wid = (int)(((long long)blockIdx.x * blockDim.x + threadIdx.x) >> 6);
    int nwaves = (gridDim.x * blockDim.x) >> 6;
    float2 z = make_float2(0.f, 0.f);
    float2 vv0 = *(const float2*)&v[i0 * HD + lane * 2];
    float2 vv1 = (nv > 1) ? *(const float2*)&v[i1 * HD + lane * 2] : z;
    float2 vv2 = (nv > 2) ? *(const float2*)&v[i2 * HD + lane * 2] : z;
    float2 vv3 = (nv > 3) ? *(const float2*)&v[i3 * HD + lane * 2] : z;
    for (int n = wid; n < N; n += nwaves) {
        float2 xv = *(const float2*)&x[(long long)n * HD + lane * 2];
        float s0 = xv.x * vv0.x + xv.y * vv0.y;
        float s1 = xv.x * vv1.x + xv.y * vv1.y;
        float s2 = xv.x * vv2.x + xv.y * vv2.y;
        float s3 = xv.x * vv3.x + xv.y * vv3.y;
        #pragma unroll
        for (int off = 32; off; off >>= 1) {
            s0 += __shfl_xor(s0, off, 64);
            s1 += __shfl_xor(s1, off, 64);
            s2 += __shfl_xor(s2, off, 64);
            s3 += __shfl_xor(s3, off, 64);
        }
        if (lane == 0) {
            o0[n] = s0;
            if (nv > 1) o1[n] = s1;
            if (nv > 2) o2[n] = s2;
            if (nv > 3) o3[n] = s3;
        }
    }
}

// ---------- H[nrows x 128] = X[nrows x 128] * W[128 x 128], fp32 ----------
__global__ __launch_bounds__(256) void k_gemm128(const float* __restrict__ X,
                                                 const float* __restrict__ W,
                                                 float* __restrict__ Hout, int nrows) {
    __shared__ float Wsh[32][132];
    __shared__ float Xsh[64][36];
    const int tid = threadIdx.x;
    const int tx = tid & 15;   // 16 col-groups x 8 cols
    const int ty = tid >> 4;   // 16 row-groups x 4 rows
    const long long row0 = (long long)blockIdx.x * 64;
    float acc[4][8];
    #pragma unroll
    for (int r = 0; r < 4; r++)
        #pragma unroll
        for (int c = 0; c < 8; c++) acc[r][c] = 0.f;

    for (int kk = 0; kk < HD; kk += 32) {
        #pragma unroll
        for (int i = 0; i < 4; i++) {           // W panel: 32x128 = 1024 float4
            int t = tid + i * 256;
            int r = t >> 5;
            int c4 = t & 31;
            float4 w4 = *(const float4*)&W[(size_t)(kk + r) * HD + c4 * 4];
            *(float4*)&Wsh[r][c4 * 4] = w4;
        }
        #pragma unroll
        for (int i = 0; i < 2; i++) {           // X panel: 64x32 = 512 float4
            int t = tid + i * 256;
            int r = t >> 3;
            int c4 = t & 7;
            long long gr = row0 + r;
            float4 x4 = make_float4(0.f, 0.f, 0.f, 0.f);
            if (gr < nrows) x4 = *(const float4*)&X[gr * HD + kk + c4 * 4];
            *(float4*)&Xsh[r][c4 * 4] = x4;
        }
        __syncthreads();
        #pragma unroll
        for (int k = 0; k < 32; k++) {
            float xv[4];
            #pragma unroll
            for (int r = 0; r < 4; r++) xv[r] = Xsh[ty * 4 + r][k];
            float4 wa = *(float4*)&Wsh[k][tx * 8];
            float4 wb = *(float4*)&Wsh[k][tx * 8 + 4];
            float wreg[8] = {wa.x, wa.y, wa.z, wa.w, wb.x, wb.y, wb.z, wb.w};
            #pragma unroll
            for (int r = 0; r < 4; r++)
                #pragma unroll
                for (int c = 0; c < 8; c++) acc[r][c] += xv[r] * wreg[c];
        }
        __syncthreads();
    }
    #pragma unroll
    for (int r = 0; r < 4; r++) {
        long long gr = row0 + ty * 4 + r;
        if (gr < nrows) {
            *(float4*)&Hout[gr * HD + tx * 8] =
                make_float4(acc[r][0], acc[r][1], acc[r][2], acc[r][3]);
            *(float4*)&Hout[gr * HD + tx * 8 + 4] =
                make_float4(acc[r][4], acc[r][5], acc[r][6], acc[r][7]);
        }
    }
}

// ---------- CSR build ----------
__global__ void k_hist(const int* __restrict__ dst, int* __restrict__ counts, int E) {
    int e = blockIdx.x * blockDim.x + threadIdx.x;
    if (e < E) atomicAdd(&counts[dst[e]], 1);
}

// per-chunk (256 elems) sums
__global__ void k_chunksum(const int* __restrict__ counts, int* __restrict__ chunkSum, int n) {
    __shared__ int sh[256];
    int i = blockIdx.x * 256 + threadIdx.x;
    sh[threadIdx.x] = (i < n) ? counts[i] : 0;
    __syncthreads();
    for (int off = 128; off; off >>= 1) {
        if (threadIdx.x < off) sh[threadIdx.x] += sh[threadIdx.x + off];
        __syncthreads();
    }
    if (threadIdx.x == 0) chunkSum[blockIdx.x] = sh[0];
}

// single-block exclusive scan over chunk sums (nChunk <= 1024)
__global__ void k_scanchunk(const int* __restrict__ chunkSum, int* __restrict__ chunkOff, int nChunk) {
    __shared__ int sh[1024];
    int t = threadIdx.x;
    int v = (t < nChunk) ? chunkSum[t] : 0;
    sh[t] = v;
    __syncthreads();
    for (int off = 1; off < 1024; off <<= 1) {
        int add = (t >= off) ? sh[t - off] : 0;
        __syncthreads();
        sh[t] += add;
        __syncthreads();
    }
    if (t < nChunk) chunkOff[t] = sh[t] - v; // exclusive
}

// per-chunk exclusive scan + chunk offset -> rowStart; also seed fillPos
__global__ void k_rowstart(const int* __restrict__ counts, const int* __restrict__ chunkOff,
                           int* __restrict__ rowStart, int* __restrict__ fillPos, int n) {
    __shared__ int sh[256];
    int i = blockIdx.x * 256 + threadIdx.x;
    int t = threadIdx.x;
    int v = (i < n) ? counts[i] : 0;
    sh[t] = v;
    __syncthreads();
    for (int off = 1; off < 256; off <<= 1) {
        int add = (t >= off) ? sh[t - off] : 0;
        __syncthreads();
        sh[t] += add;
        __syncthreads();
    }
    if (i < n) {
        int rs = chunkOff[blockIdx.x] + sh[t] - v;
        rowStart[i] = rs;
        fillPos[i] = rs;
    }
}

__global__ void k_fill(const int* __restrict__ src, const int* __restrict__ dst,
                       int* __restrict__ fillPos, int* __restrict__ eSrc, int E) {
    int e = blockIdx.x * blockDim.x + threadIdx.x;
    if (e >= E) return;
    int p = atomicAdd(&fillPos[dst[e]], 1);
    eSrc[p] = src[e];
}

// ---------- fused per-dst softmax + gather-aggregate, wave per dst row ----------
// out[d] += sum_e softmax(e) * hs[src_e]   (non-atomic: wave owns the row)
__global__ __launch_bounds__(256) void k_agg(const int* __restrict__ eSrc,
                                             const int* __restrict__ rowStart,
                                             const int* __restrict__ counts,
                                             const float* __restrict__ as_,
                                             const float* __restrict__ ad_,
                                             const float* __restrict__ hs,
                                             float* __restrict__ out, int Nd) {
    int lane = threadIdx.x & 63;
    int d = (int)(((long long)blockIdx.x * blockDim.x + threadIdx.x) >> 6);
    if (d >= Nd) return;
    int dg = counts[d];
    if (dg == 0) return;
    int base = rowStart[d];
    float ad = ad_[d];

    // pass 1: segment max
    float m = -1e30f;
    for (int i = lane; i < dg; i += 64)
        m = fmaxf(m, lrelu(as_[eSrc[base + i]] + ad));
    #pragma unroll
    for (int off = 32; off; off >>= 1) m = fmaxf(m, __shfl_xor(m, off, 64));

    // pass 2: denominator
    float den = 0.f;
    for (int i = lane; i < dg; i += 64)
        den += __expf(lrelu(as_[eSrc[base + i]] + ad) - m);
    #pragma unroll
    for (int off = 32; off; off >>= 1) den += __shfl_xor(den, off, 64);
    float inv = 1.f / den; // den >= 1 (max edge contributes exp(0))

    // pass 3: weighted gather
    float2 acc = make_float2(0.f, 0.f);
    for (int j0 = 0; j0 < dg; j0 += 64) {
        int n = min(64, dg - j0);
        int s = 0;
        float w = 0.f;
        if (lane < n) {
            s = eSrc[base + j0 + lane];
            w = __expf(lrelu(as_[s] + ad) - m) * inv;
        }
        for (int jj = 0; jj < n; ++jj) {
            int sj = __shfl(s, jj, 64);
            float wj = __shfl(w, jj, 64);
            float2 h = *(const float2*)&hs[(long long)sj * HD + lane * 2];
            acc.x += wj * h.x;
            acc.y += wj * h.y;
        }
    }
    float2 o = *(float2*)&out[(long long)d * HD + lane * 2];
    o.x += acc.x;
    o.y += acc.y;
    *(float2*)&out[(long long)d * HD + lane * 2] = o;
}

extern "C" void kernel_launch(void* const* d_in, const int* in_sizes, int n_in,
                              void* d_out, int out_size, void* d_ws, size_t ws_size,
                              hipStream_t stream) {
    const float* x_artist  = (const float*)d_in[0];
    const float* x_artwork = (const float*)d_in[1];
    const int* srcA[3] = {(const int*)d_in[2], (const int*)d_in[4], (const int*)d_in[6]};
    const int* dstA[3] = {(const int*)d_in[3], (const int*)d_in[5], (const int*)d_in[7]};
    const float* Ws  = (const float*)d_in[8];
    const float* a_s = (const float*)d_in[10];
    const float* a_d = (const float*)d_in[11];
    const float* Wd  = (const float*)d_in[9];
    const float* b   = (const float*)d_in[12];
    float* out = (float*)d_out;

    const int Na = in_sizes[0] / HD;
    const int Nw = in_sizes[1] / HD;
    const int E  = in_sizes[2];
    const int nTot = Nw + Na + Nw;              // concatenated dst-node space
    const int nChunk = (nTot + 255) / 256;      // <= 1024 required

    // ---- workspace carve-up (4-byte elements) ----
    float* ws = (float*)d_ws;
    size_t off = 0;
    float* v   = ws + off;  off += 768;
    float* as0 = ws + off;  off += Na;
    float* ad0 = ws + off;  off += Nw;
    float* as1 = ws + off;  off += Nw;
    float* ad1 = ws + off;  off += Na;
    float* as2 = ws + off;  off += Nw;
    float* ad2 = ws + off;  off += Nw;
    int* counts   = (int*)(ws + off); off += nTot;
    int* chunkSum = (int*)(ws + off); off += 1024;
    int* chunkOff = (int*)(ws + off); off += 1024;
    int* rowStart = (int*)(ws + off); off += nTot;
    int* fillPos  = (int*)(ws + off); off += nTot;
    int* eSrc     = (int*)(ws + off); off += (size_t)3 * E;
    float* hs     = ws + off;         off += (size_t)Nw * HD;
    if (ws_size < off * sizeof(float) || nChunk > 1024) return;

    // per-conv metadata
    const float* xsrc[3]  = {x_artist, x_artwork, x_artwork};
    const int    nsrc[3]  = {Na, Nw, Nw};
    const float* asP[3]   = {as0, as1, as2};
    const float* adP[3]   = {ad0, ad1, ad2};
    const int statOff[3]  = {0, Nw, Nw + Na};
    const int ndst[3]     = {Nw, Na, Nw};
    const long long outBase[3] = {(long long)Na * HD, 0, (long long)Na * HD};

    const long long total4 = (long long)(Na + Nw) * (HD / 4);
    const int B = 256;

    k_init_out<<<(unsigned)((total4 + B - 1) / B), B, 0, stream>>>(out, b, Na, Nw);
    k_zero_int<<<(nTot + B - 1) / B, B, 0, stream>>>(counts, nTot);
    k_vvec<<<3, B, 0, stream>>>(Ws, Wd, a_s, a_d, v);

    // alphas: artist pass (slots vs0=0, vd1=3), artwork pass (vd0=1, vs1=2, vs2=4, vd2=5)
    k_alpha<<<1024, B, 0, stream>>>(x_artist, Na, v, 0, 3, 0, 0, as0, ad1, nullptr, nullptr, 2);
    k_alpha<<<1024, B, 0, stream>>>(x_artwork, Nw, v, 1, 2, 4, 5, ad0, as1, as2, ad2, 4);

    // CSR build over concatenated dst space
    for (int c = 0; c < 3; c++)
        k_hist<<<(E + B - 1) / B, B, 0, stream>>>(dstA[c], counts + statOff[c], E);
    k_chunksum<<<nChunk, B, 0, stream>>>(counts, chunkSum, nTot);
    k_scanchunk<<<1, 1024, 0, stream>>>(chunkSum, chunkOff, nChunk);
    k_rowstart<<<nChunk, B, 0, stream>>>(counts, chunkOff, rowStart, fillPos, nTot);
    for (int c = 0; c < 3; c++)
        k_fill<<<(E + B - 1) / B, B, 0, stream>>>(srcA[c], dstA[c], fillPos + statOff[c], eSrc, E);

    // per conv: hs GEMM (shared scratch) then gather-aggregate into d_out
    for (int c = 0; c < 3; c++) {
        k_gemm128<<<(nsrc[c] + 63) / 64, B, 0, stream>>>(xsrc[c], Ws + (size_t)c * HD * HD,
                                                         hs, nsrc[c]);
        int nblk = (ndst[c] + 3) / 4; // 4 waves per 256-thread block, wave per dst
        k_agg<<<nblk, B, 0, stream>>>(eSrc, rowStart + statOff[c], counts + statOff[c],
                                      asP[c], adP[c], hs, out + outBase[c], ndst[c]);
    }

    k_relu<<<(unsigned)((total4 + B - 1) / B), B, 0, stream>>>(out, total4);
}

// Round 3
// 515.184 us; speedup vs baseline: 3.8939x; 1.2876x over previous
//
#include <hip/hip_runtime.h>
#include <hip/hip_bf16.h>

#define HD 128
#define NEG_SLOPE 0.2f

typedef __attribute__((ext_vector_type(8))) short short8;
typedef __attribute__((ext_vector_type(4))) float f32x4;

__device__ __forceinline__ float lrelu(float x) {
    return x > 0.f ? x : NEG_SLOPE * x;
}
__device__ __forceinline__ ushort f2bf(float f) {
    __hip_bfloat16 h = __float2bfloat16(f);
    return *(ushort*)&h;
}

// ---------- init d_out with biases ----------
// rows [0,Na): b[1];  rows [Na,Na+Nw): b[0]+b[2]
__global__ void k_init_out(float* __restrict__ out, const float* __restrict__ b,
                           int Na, int Nw) {
    long long idx = (long long)blockIdx.x * blockDim.x + threadIdx.x; // float4 units
    long long total4 = (long long)(Na + Nw) * (HD / 4);
    if (idx >= total4) return;
    int col4 = (int)(idx & (HD / 4 - 1));
    long long row = idx >> 5; // /32
    float4 bv;
    if (row < Na) {
        bv = *(const float4*)&b[1 * HD + col4 * 4];
    } else {
        float4 v0 = *(const float4*)&b[0 * HD + col4 * 4];
        float4 v2 = *(const float4*)&b[2 * HD + col4 * 4];
        bv = make_float4(v0.x + v2.x, v0.y + v2.y, v0.z + v2.z, v0.w + v2.w);
    }
    *(float4*)&out[idx * 4] = bv;
}

__global__ void k_zero_int(int* __restrict__ p, int n) {
    int idx = blockIdx.x * blockDim.x + threadIdx.x;
    if (idx < n) p[idx] = 0;
}

// ---------- v[c][sd][d] = sum_h W[c][d][h] * a[c][h] ----------
__global__ void k_vvec(const float* __restrict__ Ws, const float* __restrict__ Wd,
                       const float* __restrict__ a_s, const float* __restrict__ a_d,
                       float* __restrict__ v) {
    int t = blockIdx.x * blockDim.x + threadIdx.x;
    if (t >= 3 * 2 * HD) return;
    int c = t >> 8;
    int sd = (t >> 7) & 1;
    int d = t & (HD - 1);
    const float* W = sd ? Wd : Ws;
    const float* a = sd ? a_d : a_s;
    const float* Wrow = W + ((size_t)c * HD + d) * HD;
    const float* av = a + c * HD;
    float s = 0.f;
    for (int h = 0; h < HD; h++) s += Wrow[h] * av[h];
    v[t] = s;
}

// ---------- Wt[c][n][k] = bf16(Ws[c][k][n]) ----------
__global__ void k_wprep(const float* __restrict__ Ws, ushort* __restrict__ Wt) {
    int t = blockIdx.x * blockDim.x + threadIdx.x;
    if (t >= 3 * HD * HD) return;
    int c = t >> 14;
    int r = t & 16383;
    int n = r >> 7, k = r & 127;
    Wt[t] = f2bf(Ws[((size_t)c << 14) + k * HD + n]);
}

// ---------- alpha[n] = x[n] . v[slot]  (up to 4 slots fused in one pass) ----------
__global__ void k_alpha(const float* __restrict__ x, int N,
                        const float* __restrict__ v,
                        int i0, int i1, int i2, int i3,
                        float* __restrict__ o0, float* __restrict__ o1,
                        float* __restrict__ o2, float* __restrict__ o3, int nv) {
    int lane = threadIdx.x & 63;
    int wid = (int)(((long long)blockIdx.x * blockDim.x + threadIdx.x) >> 6);
    int nwaves = (gridDim.x * blockDim.x) >> 6;
    float2 z = make_float2(0.f, 0.f);
    float2 vv0 = *(const float2*)&v[i0 * HD + lane * 2];
    float2 vv1 = (nv > 1) ? *(const float2*)&v[i1 * HD + lane * 2] : z;
    float2 vv2 = (nv > 2) ? *(const float2*)&v[i2 * HD + lane * 2] : z;
    float2 vv3 = (nv > 3) ? *(const float2*)&v[i3 * HD + lane * 2] : z;
    for (int n = wid; n < N; n += nwaves) {
        float2 xv = *(const float2*)&x[(long long)n * HD + lane * 2];
        float s0 = xv.x * vv0.x + xv.y * vv0.y;
        float s1 = xv.x * vv1.x + xv.y * vv1.y;
        float s2 = xv.x * vv2.x + xv.y * vv2.y;
        float s3 = xv.x * vv3.x + xv.y * vv3.y;
        #pragma unroll
        for (int off = 32; off; off >>= 1) {
            s0 += __shfl_xor(s0, off, 64);
            s1 += __shfl_xor(s1, off, 64);
            s2 += __shfl_xor(s2, off, 64);
            s3 += __shfl_xor(s3, off, 64);
        }
        if (lane == 0) {
            o0[n] = s0;
            if (nv > 1) o1[n] = s1;
            if (nv > 2) o2[n] = s2;
            if (nv > 3) o3[n] = s3;
        }
    }
}

// ---------- H16[nrows x 128] (bf16) = X[nrows x 128] (fp32) * Wt^T, MFMA ----------
// Wt is [128 n][128 k] bf16 (pre-transposed). Block: 256 thr = 4 waves, 64 rows.
// Wave computes 16 rows x 128 cols via 8 N-frags, K-loop 4 steps of 32.
__global__ __launch_bounds__(256) void k_gemm_mfma(const float* __restrict__ X,
                                                   const ushort* __restrict__ Wt,
                                                   ushort* __restrict__ H16, int nrows) {
    int tid = threadIdx.x;
    int lane = tid & 63;
    int wv = tid >> 6;
    int m = lane & 15;      // A row within 16 / C col within 16
    int kb = lane >> 4;     // k-block 0..3
    long long row0 = (long long)blockIdx.x * 64 + wv * 16;
    long long ar = row0 + m;
    if (ar >= nrows) ar = nrows - 1;               // clamped read, store guarded
    const float* aptr = X + ar * HD + kb * 8;
    const ushort* bptr = Wt + (size_t)m * HD + kb * 8;

    f32x4 acc[8];
    #pragma unroll
    for (int t = 0; t < 8; t++) acc[t] = (f32x4){0.f, 0.f, 0.f, 0.f};

    #pragma unroll
    for (int ks = 0; ks < 4; ks++) {
        float4 a0 = *(const float4*)(aptr + ks * 32);
        float4 a1 = *(const float4*)(aptr + ks * 32 + 4);
        short8 af;
        af[0] = (short)f2bf(a0.x); af[1] = (short)f2bf(a0.y);
        af[2] = (short)f2bf(a0.z); af[3] = (short)f2bf(a0.w);
        af[4] = (short)f2bf(a1.x); af[5] = (short)f2bf(a1.y);
        af[6] = (short)f2bf(a1.z); af[7] = (short)f2bf(a1.w);
        #pragma unroll
        for (int t = 0; t < 8; t++) {
            short8 bf = *(const short8*)(bptr + (size_t)t * 16 * HD + ks * 32);
            acc[t] = __builtin_amdgcn_mfma_f32_16x16x32_bf16(af, bf, acc[t], 0, 0, 0);
        }
    }
    int rb = (lane >> 4) * 4;
    #pragma unroll
    for (int t = 0; t < 8; t++) {
        #pragma unroll
        for (int j = 0; j < 4; j++) {
            long long r = row0 + rb + j;
            if (r < nrows) H16[r * HD + t * 16 + m] = f2bf(acc[t][j]);
        }
    }
}

// ---------- CSR build ----------
__global__ void k_hist(const int* __restrict__ dst, int* __restrict__ counts, int E) {
    int e = blockIdx.x * blockDim.x + threadIdx.x;
    if (e < E) atomicAdd(&counts[dst[e]], 1);
}

__global__ void k_chunksum(const int* __restrict__ counts, int* __restrict__ chunkSum, int n) {
    __shared__ int sh[256];
    int i = blockIdx.x * 256 + threadIdx.x;
    sh[threadIdx.x] = (i < n) ? counts[i] : 0;
    __syncthreads();
    for (int off = 128; off; off >>= 1) {
        if (threadIdx.x < off) sh[threadIdx.x] += sh[threadIdx.x + off];
        __syncthreads();
    }
    if (threadIdx.x == 0) chunkSum[blockIdx.x] = sh[0];
}

__global__ void k_scanchunk(const int* __restrict__ chunkSum, int* __restrict__ chunkOff, int nChunk) {
    __shared__ int sh[1024];
    int t = threadIdx.x;
    int v = (t < nChunk) ? chunkSum[t] : 0;
    sh[t] = v;
    __syncthreads();
    for (int off = 1; off < 1024; off <<= 1) {
        int add = (t >= off) ? sh[t - off] : 0;
        __syncthreads();
        sh[t] += add;
        __syncthreads();
    }
    if (t < nChunk) chunkOff[t] = sh[t] - v; // exclusive
}

__global__ void k_rowstart(const int* __restrict__ counts, const int* __restrict__ chunkOff,
                           int* __restrict__ rowStart, int* __restrict__ fillPos, int n) {
    __shared__ int sh[256];
    int i = blockIdx.x * 256 + threadIdx.x;
    int t = threadIdx.x;
    int v = (i < n) ? counts[i] : 0;
    sh[t] = v;
    __syncthreads();
    for (int off = 1; off < 256; off <<= 1) {
        int add = (t >= off) ? sh[t - off] : 0;
        __syncthreads();
        sh[t] += add;
        __syncthreads();
    }
    if (i < n) {
        int rs = chunkOff[blockIdx.x] + sh[t] - v;
        rowStart[i] = rs;
        fillPos[i] = rs;
    }
}

__global__ void k_fill(const int* __restrict__ src, const int* __restrict__ dst,
                       int* __restrict__ fillPos, int* __restrict__ eSrc, int E) {
    int e = blockIdx.x * blockDim.x + threadIdx.x;
    if (e >= E) return;
    int p = atomicAdd(&fillPos[dst[e]], 1);
    eSrc[p] = src[e];
}

// ---------- fused per-dst softmax + gather-aggregate (+optional relu) ----------
// wave per dst row; single-pass for dg<=64 (alphas kept in registers)
template<bool RELU>
__global__ __launch_bounds__(256) void k_agg(const int* __restrict__ eSrc,
                                             const int* __restrict__ rowStart,
                                             const int* __restrict__ counts,
                                             const float* __restrict__ as_,
                                             const float* __restrict__ ad_,
                                             const ushort* __restrict__ hs,
                                             float* __restrict__ out, int Nd) {
    int lane = threadIdx.x & 63;
    int d = (int)(((long long)blockIdx.x * blockDim.x + threadIdx.x) >> 6);
    if (d >= Nd) return;
    int dg = counts[d];
    if (dg == 0 && !RELU) return;
    float2 o = *(float2*)&out[(long long)d * HD + lane * 2];
    if (dg != 0) {
        int base = rowStart[d];
        float ad = ad_[d];
        float2 acc = make_float2(0.f, 0.f);
        const ushort* hp = hs + lane * 2;
        if (dg <= 64) {
            int s = 0;
            float av = -1e30f;
            if (lane < dg) { s = eSrc[base + lane]; av = lrelu(as_[s] + ad); }
            float mm = av;
            #pragma unroll
            for (int off = 32; off; off >>= 1) mm = fmaxf(mm, __shfl_xor(mm, off, 64));
            float w = (lane < dg) ? __expf(av - mm) : 0.f;
            float den = w;
            #pragma unroll
            for (int off = 32; off; off >>= 1) den += __shfl_xor(den, off, 64);
            w *= (1.f / den);   // den >= 1 (max edge contributes exp(0))
            int jj = 0;
            for (; jj + 2 <= dg; jj += 2) {
                int s0 = __shfl(s, jj, 64), s1 = __shfl(s, jj + 1, 64);
                float w0 = __shfl(w, jj, 64), w1 = __shfl(w, jj + 1, 64);
                unsigned u0 = *(const unsigned*)(hp + (size_t)s0 * HD);
                unsigned u1 = *(const unsigned*)(hp + (size_t)s1 * HD);
                acc.x += w0 * __uint_as_float(u0 << 16) + w1 * __uint_as_float(u1 << 16);
                acc.y += w0 * __uint_as_float(u0 & 0xffff0000u) + w1 * __uint_as_float(u1 & 0xffff0000u);
            }
            if (jj < dg) {
                int s0 = __shfl(s, jj, 64);
                float w0 = __shfl(w, jj, 64);
                unsigned u0 = *(const unsigned*)(hp + (size_t)s0 * HD);
                acc.x += w0 * __uint_as_float(u0 << 16);
                acc.y += w0 * __uint_as_float(u0 & 0xffff0000u);
            }
        } else {
            float mm = -1e30f;
            for (int i = lane; i < dg; i += 64)
                mm = fmaxf(mm, lrelu(as_[eSrc[base + i]] + ad));
            #pragma unroll
            for (int off = 32; off; off >>= 1) mm = fmaxf(mm, __shfl_xor(mm, off, 64));
            float den = 0.f;
            for (int i = lane; i < dg; i += 64)
                den += __expf(lrelu(as_[eSrc[base + i]] + ad) - mm);
            #pragma unroll
            for (int off = 32; off; off >>= 1) den += __shfl_xor(den, off, 64);
            float inv = 1.f / den;
            for (int j0 = 0; j0 < dg; j0 += 64) {
                int n = min(64, dg - j0);
                int s = 0; float w = 0.f;
                if (lane < n) {
                    s = eSrc[base + j0 + lane];
                    w = __expf(lrelu(as_[s] + ad) - mm) * inv;
                }
                for (int t = 0; t < n; ++t) {
                    int sj = __shfl(s, t, 64);
                    float wj = __shfl(w, t, 64);
                    unsigned u = *(const unsigned*)(hp + (size_t)sj * HD);
                    acc.x += wj * __uint_as_float(u << 16);
                    acc.y += wj * __uint_as_float(u & 0xffff0000u);
                }
            }
        }
        o.x += acc.x;
        o.y += acc.y;
    }
    if (RELU) { o.x = fmaxf(o.x, 0.f); o.y = fmaxf(o.y, 0.f); }
    *(float2*)&out[(long long)d * HD + lane * 2] = o;
}

extern "C" void kernel_launch(void* const* d_in, const int* in_sizes, int n_in,
                              void* d_out, int out_size, void* d_ws, size_t ws_size,
                              hipStream_t stream) {
    const float* x_artist  = (const float*)d_in[0];
    const float* x_artwork = (const float*)d_in[1];
    const int* srcA[3] = {(const int*)d_in[2], (const int*)d_in[4], (const int*)d_in[6]};
    const int* dstA[3] = {(const int*)d_in[3], (const int*)d_in[5], (const int*)d_in[7]};
    const float* Ws  = (const float*)d_in[8];
    const float* Wd  = (const float*)d_in[9];
    const float* a_s = (const float*)d_in[10];
    const float* a_d = (const float*)d_in[11];
    const float* b   = (const float*)d_in[12];
    float* out = (float*)d_out;

    const int Na = in_sizes[0] / HD;
    const int Nw = in_sizes[1] / HD;
    const int E  = in_sizes[2];
    const int nTot = Nw + Na + Nw;              // concatenated dst-node space
    const int nChunk = (nTot + 255) / 256;      // <= 1024 required

    // ---- workspace carve-up (4-byte words; all chunks 16B-aligned) ----
    float* ws = (float*)d_ws;
    size_t off = 0;
    float* v   = ws + off;  off += 768;
    float* as0 = ws + off;  off += Na;
    float* ad0 = ws + off;  off += Nw;
    float* as1 = ws + off;  off += Nw;
    float* ad1 = ws + off;  off += Na;
    float* as2 = ws + off;  off += Nw;
    float* ad2 = ws + off;  off += Nw;
    int* counts   = (int*)(ws + off); off += nTot;
    int* chunkSum = (int*)(ws + off); off += 1024;
    int* chunkOff = (int*)(ws + off); off += 1024;
    int* rowStart = (int*)(ws + off); off += nTot;
    int* fillPos  = (int*)(ws + off); off += nTot;
    int* eSrc     = (int*)(ws + off); off += (size_t)3 * E;
    ushort* Wt    = (ushort*)(ws + off); off += (3 * HD * HD) / 2;
    ushort* hs16  = (ushort*)(ws + off); off += (size_t)Nw * HD / 2;
    if (ws_size < off * sizeof(float) || nChunk > 1024) return;

    // per-conv metadata
    const float* xsrc[3]  = {x_artist, x_artwork, x_artwork};
    const int    nsrc[3]  = {Na, Nw, Nw};
    const float* asP[3]   = {as0, as1, as2};
    const float* adP[3]   = {ad0, ad1, ad2};
    const int statOff[3]  = {0, Nw, Nw + Na};
    const int ndst[3]     = {Nw, Na, Nw};
    const long long outBase[3] = {(long long)Na * HD, 0, (long long)Na * HD};

    const long long total4 = (long long)(Na + Nw) * (HD / 4);
    const int B = 256;

    k_init_out<<<(unsigned)((total4 + B - 1) / B), B, 0, stream>>>(out, b, Na, Nw);
    k_zero_int<<<(nTot + B - 1) / B, B, 0, stream>>>(counts, nTot);
    k_vvec<<<3, B, 0, stream>>>(Ws, Wd, a_s, a_d, v);
    k_wprep<<<(3 * HD * HD + B - 1) / B, B, 0, stream>>>(Ws, Wt);

    // alphas: artist pass (slots vs0=0, vd1=3), artwork pass (vd0=1, vs1=2, vs2=4, vd2=5)
    k_alpha<<<1024, B, 0, stream>>>(x_artist, Na, v, 0, 3, 0, 0, as0, ad1, nullptr, nullptr, 2);
    k_alpha<<<1024, B, 0, stream>>>(x_artwork, Nw, v, 1, 2, 4, 5, ad0, as1, as2, ad2, 4);

    // CSR build over concatenated dst space
    for (int c = 0; c < 3; c++)
        k_hist<<<(E + B - 1) / B, B, 0, stream>>>(dstA[c], counts + statOff[c], E);
    k_chunksum<<<nChunk, B, 0, stream>>>(counts, chunkSum, nTot);
    k_scanchunk<<<1, 1024, 0, stream>>>(chunkSum, chunkOff, nChunk);
    k_rowstart<<<nChunk, B, 0, stream>>>(counts, chunkOff, rowStart, fillPos, nTot);
    for (int c = 0; c < 3; c++)
        k_fill<<<(E + B - 1) / B, B, 0, stream>>>(srcA[c], dstA[c], fillPos + statOff[c], eSrc, E);

    // per conv: hs GEMM (bf16 out, shared scratch) then gather-aggregate into d_out
    // relu fused into the LAST writer of each output block: conv1 (artist), conv2 (artwork)
    for (int c = 0; c < 3; c++) {
        k_gemm_mfma<<<(nsrc[c] + 63) / 64, B, 0, stream>>>(xsrc[c], Wt + (size_t)c * HD * HD,
                                                           hs16, nsrc[c]);
        int nblk = (ndst[c] + 3) / 4; // 4 waves per 256-thread block, wave per dst
        if (c == 0)
            k_agg<false><<<nblk, B, 0, stream>>>(eSrc, rowStart + statOff[c], counts + statOff[c],
                                                 asP[c], adP[c], hs16, out + outBase[c], ndst[c]);
        else
            k_agg<true><<<nblk, B, 0, stream>>>(eSrc, rowStart + statOff[c], counts + statOff[c],
                                                asP[c], adP[c], hs16, out + outBase[c], ndst[c]);
    }
}